// Round 9
// baseline (245.893 us; speedup 1.0000x reference)
//
#include <hip/hip_runtime.h>

#define NN 20000
#define EE 320000
#define CAP 64           // slab slots per node (in-degree ~ Poisson(16))
#define SVC 72           // per-wave edge capacity (CAP + ovf slack + self)
#define OVCAP 8192
#define DSTR 8           // degcnt stride in u64: one node per 64B cache line

// consts layout (float offsets)
#define WZ_O 0
#define BZ_O 512
#define WH_O 576
#define BH_O 1088
#define OWT_O 1152       // transposed+padded out weights: [p][68] (k<64 valid)
#define OB_O 1968
#define PR_O 1980
#define NCONST 1992

__device__ __forceinline__ float b2f(unsigned short h) {
  union { unsigned int u; float f; } v; v.u = ((unsigned int)h) << 16; return v.f;
}
__device__ __forceinline__ unsigned short f2b(float f) {
  union { unsigned int u; float f; } v; v.f = f;
  unsigned int u = v.u;
  unsigned int r = (u + 0x7fffu + ((u >> 16) & 1u)) >> 16;  // RNE
  return (unsigned short)r;
}
__device__ __forceinline__ float ldw(const void* p, int i, int isbf) {
  return isbf ? b2f(((const unsigned short*)p)[i]) : ((const float*)p)[i];
}
__device__ __forceinline__ void upk(unsigned int w, float& x0, float& x1) {
  union { unsigned int u; float f; } lo, hi;
  lo.u = w << 16; hi.u = w & 0xffff0000u;
  x0 = lo.f; x1 = hi.f;
}
__device__ __forceinline__ float degf(unsigned long long dc) {
  return (float)(unsigned int)dc * (1.0f / 1048576.0f);
}

struct __attribute__((aligned(4))) U3 { unsigned int x, y, z; };   // 12B, align 4
struct __attribute__((aligned(8))) F6 { float f0,f1,f2,f3,f4,f5; }; // 24B, align 8

// 1) init: zero padded degcnt + ovf_cnt; block 0: dtype detect + fused-weight prep
__global__ void k_init(const unsigned int* __restrict__ ei_w,
                       const unsigned int* __restrict__ ea_w,
                       int* __restrict__ flags,
                       unsigned long long* __restrict__ degcnt,
                       int* __restrict__ ovf_cnt,
                       float* __restrict__ consts,
                       const void* czw, const void* czb,
                       const void* chw, const void* chb,
                       const void* lzw, const void* lzb,
                       const void* lhw, const void* lhb,
                       const void* att, const void* ow, const void* ob) {
  int tid = threadIdx.x;
  int i = blockIdx.x * 256 + tid;
  if (i < NN) degcnt[i * DSTR] = 0ull;
  if (blockIdx.x == 1 && tid == 0) *ovf_cnt = 0;
  if (blockIdx.x != 0) return;

  __shared__ int sfl[2];
  if (tid < 64) {
    // edge_attr in (0,1): packed-bf16 words have sign bits 15/31 == 0; f32 words random bit15
    unsigned long long b1 = __ballot((ea_w[tid] >> 15) & 1u);
    // edge_index < 20000: int64 arrays have all odd 32-bit words == 0
    unsigned long long b2 = __ballot(ei_w[2 * tid + 1] != 0u);
    if (tid == 0) {
      int f0 = (b1 == 0ull) ? 1 : 0;   // 1 = floats are bf16
      int f1 = (b2 == 0ull) ? 1 : 0;   // 1 = indices are int64
      flags[0] = f0; flags[1] = f1; sfl[0] = f0; sfl[1] = f1;
    }
  }
  __syncthreads();
  int isbf = sfl[0];

  // fused gate weights: Wz = conv_z_w @ lin_z_w[:64], Wh = conv_h_w @ lin_h_w[:64]
  for (int idx = tid; idx < 512; idx += 256) {
    int f = idx >> 6, k = idx & 63;
    float sz = 0.f, sh = 0.f;
    for (int h = 0; h < 64; ++h) {
      sz += ldw(czw, f * 64 + h, isbf) * ldw(lzw, h * 64 + k, isbf);
      sh += ldw(chw, f * 64 + h, isbf) * ldw(lhw, h * 64 + k, isbf);
    }
    consts[WZ_O + idx] = sz; consts[WH_O + idx] = sh;
  }
  for (int idx = tid; idx < 64; idx += 256) {
    float sz = ldw(lzb, idx, isbf), sh = ldw(lhb, idx, isbf);
    for (int h = 0; h < 64; ++h) {
      sz += ldw(czb, h, isbf) * ldw(lzw, h * 64 + idx, isbf);
      sh += ldw(chb, h, isbf) * ldw(lhw, h * 64 + idx, isbf);
    }
    consts[BZ_O + idx] = sz; consts[BH_O + idx] = sh;
  }
  // out weights transposed [p][k], row-padded to 68
  for (int idx = tid; idx < 816; idx += 256) {
    int p = idx / 68, kk = idx % 68;
    consts[OWT_O + idx] = (kk < 64) ? ldw(ow, kk * 12 + p, isbf) : 0.f;
  }
  if (tid < 12) consts[OB_O + tid] = ldw(ob, tid, isbf);
  if (tid == 0) {
    float a[12]; float m = -1e30f;
    for (int p = 0; p < 12; ++p) { a[p] = ldw(att, p, isbf); m = fmaxf(m, a[p]); }
    float ssum = 0.f;
    for (int p = 0; p < 12; ++p) { a[p] = __expf(a[p] - m); ssum += a[p]; }
    for (int p = 0; p < 12; ++p) consts[PR_O + p] = a[p] / ssum;
  }
}

// 2) single-pass adjacency build: one packed 64-bit atomic per edge gives BOTH the
//    slot index (count, hi32) and the weighted-degree accumulation (fixed point, lo32).
//    degcnt is line-padded: one node per 64B line -> no false line sharing.
__global__ void k_append(const void* __restrict__ ei, const void* __restrict__ ea,
                         const int* __restrict__ flags,
                         unsigned long long* __restrict__ degcnt,
                         unsigned int* __restrict__ slab,
                         int* __restrict__ ovf_cnt, int* __restrict__ ovf_dst,
                         unsigned int* __restrict__ ovf_pack) {
  int isbf = flags[0], is64 = flags[1];
  int e = blockIdx.x * blockDim.x + threadIdx.x;
  if (e >= EE) return;
  int r, c;
  if (is64) {
    r = (int)((const unsigned int*)ei)[2 * e];
    c = (int)((const unsigned int*)ei)[2 * (EE + e)];
  } else {
    r = ((const int*)ei)[e];
    c = ((const int*)ei)[EE + e];
  }
  unsigned short wb;
  float w;
  if (isbf) { wb = ((const unsigned short*)ea)[e]; w = b2f(wb); }
  else      { w = ((const float*)ea)[e]; wb = f2b(w); }
  unsigned long long pk = (1ull << 32) |
      (unsigned long long)(unsigned int)__float2int_rn(w * 1048576.0f);
  unsigned long long old = atomicAdd(&degcnt[c * DSTR], pk);
  int pos = (int)(old >> 32);
  unsigned int packed = ((unsigned int)wb << 16) | (unsigned int)r;
  if (pos < CAP) {
    slab[c * CAP + pos] = packed;
  } else {
    int oi = atomicAdd(ovf_cnt, 1);
    if (oi < OVCAP) { ovf_dst[oi] = c; ovf_pack[oi] = packed; }
  }
}

#define ACC6(u, v)                                           \
  { float x0, x1;                                            \
    upk((u).x, x0, x1); a[0] += (v) * x0; a[1] += (v) * x1;  \
    upk((u).y, x0, x1); a[2] += (v) * x0; a[3] += (v) * x1;  \
    upk((u).z, x0, x1); a[4] += (v) * x0; a[5] += (v) * x1; }

#define ACCF6(u, v)                                                     \
  { a[0] += (v) * (u).f0; a[1] += (v) * (u).f1; a[2] += (v) * (u).f2;   \
    a[3] += (v) * (u).f3; a[4] += (v) * (u).f4; a[5] += (v) * (u).f5; }

// 3) barrier-free wave-per-node: 4 waves/block, each wave owns one node end-to-end.
//    Gather uses all 64 lanes x 6 payload elems (384 = 64*6).
__global__ void __launch_bounds__(256) k_node(
    const void* __restrict__ x,
    const unsigned long long* __restrict__ degcnt,
    const unsigned int* __restrict__ slab,
    const int* __restrict__ ovf_cnt, const int* __restrict__ ovf_dst,
    const unsigned int* __restrict__ ovf_pack,
    const float* __restrict__ consts, const int* __restrict__ flags,
    void* __restrict__ out) {
  __shared__ __align__(16) float sow[840];        // owT 816 | ob 12 | pr 12
  __shared__ __align__(16) int2  sv[4 * SVC];     // per-wave edges {soff, v-bits}
  __shared__ __align__(16) float accT[4 * 384];   // per-wave [b][p][f]
  __shared__ __align__(16) float hw[4 * 272];     // per-wave [b][68]
  __shared__ int swcnt[4];

  const int tid  = threadIdx.x;
  const int w    = tid >> 6;
  const int lane = tid & 63;
  const int isbf = flags[0];
  const int n    = blockIdx.x * 4 + w;

  for (int i = tid; i < 840; i += 256) sow[i] = consts[OWT_O + i];
  float wz[8], wh[8];
#pragma unroll
  for (int f = 0; f < 8; ++f) {
    wz[f] = consts[WZ_O + f * 64 + lane];
    wh[f] = consts[WH_O + f * 64 + lane];
  }
  const float bz = consts[BZ_O + lane], bh = consts[BH_O + lane];

  // --- stage this wave's edges into its LDS slab ---
  unsigned long long dcn = degcnt[n * DSTR];
  int cnt = (int)(dcn >> 32);
  int base = cnt < CAP ? cnt : CAP;
  const float dn = rsqrtf(degf(dcn) + 1.0f);
  int2* svw = &sv[w * SVC];
  if (lane == 0) swcnt[w] = base;
  if (lane < base) {
    unsigned int pk = slab[n * CAP + lane];
    int s = (int)(pk & 0xffffu);
    float v = b2f((unsigned short)(pk >> 16)) * rsqrtf(degf(degcnt[s * DSTR]) + 1.0f);
    svw[lane] = make_int2(s * 96, __float_as_int(v));
  }
  int m0 = base;
  {
    int ov = ovf_cnt[0];                 // expected 0
    if (ov > 0) {
      if (ov > OVCAP) ov = OVCAP;
      for (int i = lane; i < ov; i += 64) {
        if (ovf_dst[i] == n) {
          int idx = atomicAdd(&swcnt[w], 1);
          if (idx < SVC - 1) {
            unsigned int pk = ovf_pack[i];
            int s = (int)(pk & 0xffffu);
            float v = b2f((unsigned short)(pk >> 16)) *
                      rsqrtf(degf(degcnt[s * DSTR]) + 1.0f);
            svw[idx] = make_int2(s * 96, __float_as_int(v));
          }
        }
      }
      __builtin_amdgcn_wave_barrier();
      m0 = swcnt[w];
      if (m0 > SVC - 1) m0 = SVC - 1;
    }
  }
  if (lane == 0) svw[m0] = make_int2(n * 96, __float_as_int(dn));  // self loop
  const int m1 = m0 + 1;
  __syncthreads();   // sow ready (cross-wave); svw writes also drained

  // --- gather: all 64 lanes; lane owns elems 6*lane..6*lane+5 of [b][f][p] ---
  float a[6];
#pragma unroll
  for (int t = 0; t < 6; ++t) a[t] = 0.f;
  {
    // b = lane/16 (96/6=16 lanes per batch; never crosses mid-lane)
    const long xbase = (long)(lane >> 4) * (NN * 96) + 6 * (lane & 15);
    if (isbf) {
      const unsigned short* xb = (const unsigned short*)x;
      int j = 0;
      for (; j + 1 < m1; j += 2) {
        int2 e0 = svw[j], e1 = svw[j + 1];
        U3 u0 = *(const U3*)(xb + xbase + e0.x);
        U3 u1 = *(const U3*)(xb + xbase + e1.x);
        float v0 = __int_as_float(e0.y), v1 = __int_as_float(e1.y);
        ACC6(u0, v0); ACC6(u1, v1);
      }
      if (j < m1) {
        int2 e0 = svw[j];
        U3 u0 = *(const U3*)(xb + xbase + e0.x);
        float v0 = __int_as_float(e0.y);
        ACC6(u0, v0);
      }
    } else {
      const float* xf = (const float*)x;
      int j = 0;
      for (; j + 1 < m1; j += 2) {
        int2 e0 = svw[j], e1 = svw[j + 1];
        F6 u0 = *(const F6*)(xf + xbase + e0.x);
        F6 u1 = *(const F6*)(xf + xbase + e1.x);
        float v0 = __int_as_float(e0.y), v1 = __int_as_float(e1.y);
        ACCF6(u0, v0); ACCF6(u1, v1);
      }
      if (j < m1) {
        int2 e0 = svw[j];
        F6 u0 = *(const F6*)(xf + xbase + e0.x);
        float v0 = __int_as_float(e0.y);
        ACCF6(u0, v0);
      }
    }
    // scatter-transpose into accT[b][p][f], scaled by dn
    float* accTw = &accT[w * 384];
#pragma unroll
    for (int t = 0; t < 6; ++t) {
      int e = 6 * lane + t;
      int b = e / 96, r = e % 96, f = r / 12, p = r % 12;
      accTw[b * 96 + p * 8 + f] = dn * a[t];
    }
  }
  __builtin_amdgcn_wave_barrier();

  // --- gates: lane = hidden index k; all 48 (b,p) pairs; h accumulated per b ---
  {
    const float* accTw = &accT[w * 384];
    float* hww = &hw[w * 272];
#pragma unroll
    for (int b = 0; b < 4; ++b) {
      float hbl = 0.f;
#pragma unroll
      for (int p = 0; p < 12; ++p) {
        const float4* A = (const float4*)&accTw[b * 96 + p * 8];
        float4 A0 = A[0], A1 = A[1];
        float za = bz + A0.x * wz[0] + A0.y * wz[1] + A0.z * wz[2] + A0.w * wz[3]
                      + A1.x * wz[4] + A1.y * wz[5] + A1.z * wz[6] + A1.w * wz[7];
        float ta = bh + A0.x * wh[0] + A0.y * wh[1] + A0.z * wh[2] + A0.w * wh[3]
                      + A1.x * wh[4] + A1.y * wh[5] + A1.z * wh[6] + A1.w * wh[7];
        // (1 - sigmoid(za)) * tanh(ta) = (eh-1) / ((1+ea)(1+eh)), ea=e^za, eh=e^{2ta}
        float ea = __expf(za);
        float eh = __expf(2.0f * fminf(ta, 40.0f));
        hbl += sow[828 + p] * (eh - 1.0f) *
               __builtin_amdgcn_rcpf((1.0f + ea) * (1.0f + eh));
      }
      hww[b * 68 + lane] = fmaxf(hbl, 0.f);   // relu
    }
  }
  __builtin_amdgcn_wave_barrier();

  // --- out projection: lane t<48 -> (b,p); vectorized b128 reads ---
  if (lane < 48) {
    const float* hww = &hw[w * 272];
    int b = lane / 12, p = lane % 12;
    float o = sow[816 + p];
#pragma unroll
    for (int kq = 0; kq < 16; ++kq) {
      float4 hv = *(const float4*)&hww[b * 68 + 4 * kq];
      float4 wv = *(const float4*)&sow[p * 68 + 4 * kq];
      o += hv.x * wv.x + hv.y * wv.y + hv.z * wv.z + hv.w * wv.w;
    }
    int oi = (b * NN + n) * 12 + p;
    if (isbf) ((unsigned short*)out)[oi] = f2b(o);
    else      ((float*)out)[oi] = o;
  }
}

extern "C" void kernel_launch(void* const* d_in, const int* in_sizes, int n_in,
                              void* d_out, int out_size, void* d_ws, size_t ws_size,
                              hipStream_t stream) {
  const void* x   = d_in[0];
  const void* ei  = d_in[1];
  const void* ea  = d_in[2];
  const void* czw = d_in[3];
  const void* czb = d_in[4];
  // d_in[5], d_in[6]: conv_r_* — dead (H0 = 0)
  const void* chw = d_in[7];
  const void* chb = d_in[8];
  const void* lzw = d_in[9];
  const void* lzb = d_in[10];
  // d_in[11], d_in[12]: lin_r_* — dead
  const void* lhw = d_in[13];
  const void* lhb = d_in[14];
  const void* att = d_in[15];
  const void* ow  = d_in[16];
  const void* ob  = d_in[17];

  // workspace ~6.5 MB
  char* ws = (char*)d_ws;
  int*   flags   = (int*)  (ws + 0);
  float* consts  = (float*)(ws + 256);          // 1992 f32 -> ends 8224
  unsigned long long* degcnt = (unsigned long long*)(ws + 8448);   // padded: 1,280,000 B
  int*   ovf_cnt = (int*)  (ws + 1288448);
  int*   ovf_dst = (int*)  (ws + 1288704);      // 32768 -> 1,321,472
  unsigned int* ovf_pack = (unsigned int*)(ws + 1321472);  // 32768 -> 1,354,240
  unsigned int* slab     = (unsigned int*)(ws + 1354240);  // 5,120,000 -> 6,474,240

  k_init<<<dim3(79), dim3(256), 0, stream>>>((const unsigned int*)ei,
                                             (const unsigned int*)ea, flags, degcnt,
                                             ovf_cnt, consts, czw, czb, chw, chb,
                                             lzw, lzb, lhw, lhb, att, ow, ob);
  k_append<<<dim3(1250), dim3(256), 0, stream>>>(ei, ea, flags, degcnt, slab,
                                                 ovf_cnt, ovf_dst, ovf_pack);
  k_node<<<dim3(NN / 4), dim3(256), 0, stream>>>(x, degcnt, slab, ovf_cnt, ovf_dst,
                                                 ovf_pack, consts, flags, d_out);
}

// Round 10
// 233.360 us; speedup vs baseline: 1.0537x; 1.0537x over previous
//
#include <hip/hip_runtime.h>

#define NN 20000
#define EE 320000
#define CAP 64           // slab slots per node (in-degree ~ Poisson(16))
#define SVC 72           // per-wave edge capacity (CAP + ovf slack + self)
#define OVCAP 8192
#define DSTR 8           // degcnt stride in u64: one node per 64B cache line
#define EBLK 313         // edge blocks: ceil(320000/1024)

// consts layout (float offsets)
#define WZ_O 0
#define BZ_O 512
#define WH_O 576
#define BH_O 1088
#define OWT_O 1152       // transposed+padded out weights: [p][68] (k<64 valid)
#define OB_O 1968
#define PR_O 1980
#define NCONST 1992

__device__ __forceinline__ float b2f(unsigned short h) {
  union { unsigned int u; float f; } v; v.u = ((unsigned int)h) << 16; return v.f;
}
__device__ __forceinline__ unsigned short f2b(float f) {
  union { unsigned int u; float f; } v; v.f = f;
  unsigned int u = v.u;
  unsigned int r = (u + 0x7fffu + ((u >> 16) & 1u)) >> 16;  // RNE
  return (unsigned short)r;
}
__device__ __forceinline__ float ldw(const void* p, int i, int isbf) {
  return isbf ? b2f(((const unsigned short*)p)[i]) : ((const float*)p)[i];
}
__device__ __forceinline__ void upk(unsigned int w, float& x0, float& x1) {
  union { unsigned int u; float f; } lo, hi;
  lo.u = w << 16; hi.u = w & 0xffff0000u;
  x0 = lo.f; x1 = hi.f;
}
__device__ __forceinline__ float degf(unsigned long long dc) {
  return (float)(unsigned int)dc * (1.0f / 1048576.0f);
}

// 1) k_append: blocks 0..EBLK-1 process 4 edges/thread (one packed 64-bit atomic
//    per edge -> slot index in hi32 + fixed-point weighted degree in lo32).
//    Block EBLK runs concurrently: dtype flags + fused-weight prep into consts.
//    Dtype detection is block-local (64-lane ballot) -> no cross-block dependency.
__global__ void __launch_bounds__(256) k_append(
    const void* __restrict__ ei, const void* __restrict__ ea,
    unsigned long long* __restrict__ degcnt,
    unsigned int* __restrict__ slab,
    int* __restrict__ ovf_cnt, int* __restrict__ ovf_dst,
    unsigned int* __restrict__ ovf_pack,
    int* __restrict__ flags, float* __restrict__ consts,
    const void* czw, const void* czb, const void* chw, const void* chb,
    const void* lzw, const void* lzb, const void* lhw, const void* lhb,
    const void* att, const void* ow, const void* ob) {
  __shared__ int sfl[2];
  const int tid = threadIdx.x;
  if (tid < 64) {
    // edge_attr in (0,1): packed-bf16 words have sign bits 15/31==0; f32 words random bit15
    unsigned long long b1 = __ballot((((const unsigned int*)ea)[tid] >> 15) & 1u);
    // edge_index < 20000: int64 arrays have all odd 32-bit words == 0
    unsigned long long b2 = __ballot(((const unsigned int*)ei)[2 * tid + 1] != 0u);
    if (tid == 0) {
      sfl[0] = (b1 == 0ull) ? 1 : 0;   // 1 = floats are bf16
      sfl[1] = (b2 == 0ull) ? 1 : 0;   // 1 = indices are int64
    }
  }
  __syncthreads();
  const int isbf = sfl[0], is64 = sfl[1];

  if (blockIdx.x == EBLK) {
    // ---- weight prep block (concurrent with edge blocks) ----
    if (tid == 0) { flags[0] = isbf; flags[1] = is64; }
    for (int idx = tid; idx < 512; idx += 256) {
      int f = idx >> 6, k = idx & 63;
      float sz = 0.f, sh = 0.f;
      for (int h = 0; h < 64; ++h) {
        sz += ldw(czw, f * 64 + h, isbf) * ldw(lzw, h * 64 + k, isbf);
        sh += ldw(chw, f * 64 + h, isbf) * ldw(lhw, h * 64 + k, isbf);
      }
      consts[WZ_O + idx] = sz; consts[WH_O + idx] = sh;
    }
    for (int idx = tid; idx < 64; idx += 256) {
      float sz = ldw(lzb, idx, isbf), sh = ldw(lhb, idx, isbf);
      for (int h = 0; h < 64; ++h) {
        sz += ldw(czb, h, isbf) * ldw(lzw, h * 64 + idx, isbf);
        sh += ldw(chb, h, isbf) * ldw(lhw, h * 64 + idx, isbf);
      }
      consts[BZ_O + idx] = sz; consts[BH_O + idx] = sh;
    }
    for (int idx = tid; idx < 816; idx += 256) {    // out weights [p][k], rows padded to 68
      int p = idx / 68, kk = idx % 68;
      consts[OWT_O + idx] = (kk < 64) ? ldw(ow, kk * 12 + p, isbf) : 0.f;
    }
    if (tid < 12) consts[OB_O + tid] = ldw(ob, tid, isbf);
    if (tid == 0) {
      float a[12]; float m = -1e30f;
      for (int p = 0; p < 12; ++p) { a[p] = ldw(att, p, isbf); m = fmaxf(m, a[p]); }
      float ssum = 0.f;
      for (int p = 0; p < 12; ++p) { a[p] = __expf(a[p] - m); ssum += a[p]; }
      for (int p = 0; p < 12; ++p) consts[PR_O + p] = a[p] / ssum;
    }
    return;
  }

  // ---- edge blocks: 4 edges per thread, independent chains ----
  const int e0 = blockIdx.x * 1024 + tid;
#pragma unroll
  for (int u = 0; u < 4; ++u) {
    int e = e0 + 256 * u;
    if (e >= EE) continue;
    int r, c;
    if (is64) {
      r = (int)((const unsigned int*)ei)[2 * e];
      c = (int)((const unsigned int*)ei)[2 * (EE + e)];
    } else {
      r = ((const int*)ei)[e];
      c = ((const int*)ei)[EE + e];
    }
    unsigned short wb;
    float w;
    if (isbf) { wb = ((const unsigned short*)ea)[e]; w = b2f(wb); }
    else      { w = ((const float*)ea)[e]; wb = f2b(w); }
    unsigned long long pk = (1ull << 32) |
        (unsigned long long)(unsigned int)__float2int_rn(w * 1048576.0f);
    unsigned long long old = atomicAdd(&degcnt[c * DSTR], pk);
    int pos = (int)(old >> 32);
    unsigned int packed = ((unsigned int)wb << 16) | (unsigned int)r;
    if (pos < CAP) {
      slab[c * CAP + pos] = packed;
    } else {
      int oi = atomicAdd(ovf_cnt, 1);
      if (oi < OVCAP) { ovf_dst[oi] = c; ovf_pack[oi] = packed; }
    }
  }
}

#define ACC8(u, v)                                           \
  { float x0, x1;                                            \
    upk((u).x, x0, x1); a[0] += (v) * x0; a[1] += (v) * x1;  \
    upk((u).y, x0, x1); a[2] += (v) * x0; a[3] += (v) * x1;  \
    upk((u).z, x0, x1); a[4] += (v) * x0; a[5] += (v) * x1;  \
    upk((u).w, x0, x1); a[6] += (v) * x0; a[7] += (v) * x1; }

#define ACCF8(u0, u1, v)                                                       \
  { a[0] += (v) * (u0).x; a[1] += (v) * (u0).y; a[2] += (v) * (u0).z;          \
    a[3] += (v) * (u0).w; a[4] += (v) * (u1).x; a[5] += (v) * (u1).y;          \
    a[6] += (v) * (u1).z; a[7] += (v) * (u1).w; }

// 2) barrier-free wave-per-node (round-8 structure): 4 waves/block, wave owns a node.
//    Gather: lanes 0..47, 16B/lane uint4 loads, 2-wide pipelined.
__global__ void __launch_bounds__(256) k_node(
    const void* __restrict__ x,
    const unsigned long long* __restrict__ degcnt,
    const unsigned int* __restrict__ slab,
    const int* __restrict__ ovf_cnt, const int* __restrict__ ovf_dst,
    const unsigned int* __restrict__ ovf_pack,
    const float* __restrict__ consts, const int* __restrict__ flags,
    void* __restrict__ out) {
  __shared__ __align__(16) float sow[840];        // owT 816 | ob 12 | pr 12
  __shared__ __align__(16) int2  sv[4 * SVC];     // per-wave edges {soff, v-bits}
  __shared__ __align__(16) float accT[4 * 384];   // per-wave [b][p][f]
  __shared__ __align__(16) float hw[4 * 272];     // per-wave [b][68]
  __shared__ int swcnt[4];

  const int tid  = threadIdx.x;
  const int w    = tid >> 6;
  const int lane = tid & 63;
  const int isbf = flags[0];
  const int n    = blockIdx.x * 4 + w;

  for (int i = tid; i < 840; i += 256) sow[i] = consts[OWT_O + i];
  float wz[8], wh[8];
#pragma unroll
  for (int f = 0; f < 8; ++f) {
    wz[f] = consts[WZ_O + f * 64 + lane];
    wh[f] = consts[WH_O + f * 64 + lane];
  }
  const float bz = consts[BZ_O + lane], bh = consts[BH_O + lane];

  // --- stage this wave's edges into its LDS slab ---
  unsigned long long dcn = degcnt[n * DSTR];
  int cnt = (int)(dcn >> 32);
  int base = cnt < CAP ? cnt : CAP;
  const float dn = rsqrtf(degf(dcn) + 1.0f);
  int2* svw = &sv[w * SVC];
  if (lane == 0) swcnt[w] = base;
  if (lane < base) {
    unsigned int pk = slab[n * CAP + lane];
    int s = (int)(pk & 0xffffu);
    float v = b2f((unsigned short)(pk >> 16)) * rsqrtf(degf(degcnt[s * DSTR]) + 1.0f);
    svw[lane] = make_int2(s * 96, __float_as_int(v));
  }
  int m0 = base;
  {
    int ov = ovf_cnt[0];                 // expected 0
    if (ov > 0) {
      if (ov > OVCAP) ov = OVCAP;
      for (int i = lane; i < ov; i += 64) {
        if (ovf_dst[i] == n) {
          int idx = atomicAdd(&swcnt[w], 1);
          if (idx < SVC - 1) {
            unsigned int pk = ovf_pack[i];
            int s = (int)(pk & 0xffffu);
            float v = b2f((unsigned short)(pk >> 16)) *
                      rsqrtf(degf(degcnt[s * DSTR]) + 1.0f);
            svw[idx] = make_int2(s * 96, __float_as_int(v));
          }
        }
      }
      __builtin_amdgcn_wave_barrier();
      m0 = swcnt[w];
      if (m0 > SVC - 1) m0 = SVC - 1;
    }
  }
  if (lane == 0) svw[m0] = make_int2(n * 96, __float_as_int(dn));  // self loop
  const int m1 = m0 + 1;
  __syncthreads();   // sow ready (cross-wave); svw writes also drained

  // --- gather: lanes 0..47, lane owns 8 payload elems; 2-wide pipelined loads ---
  float a[8];
#pragma unroll
  for (int t = 0; t < 8; ++t) a[t] = 0.f;
  if (lane < 48) {
    const long xbase = (long)(lane / 12) * (NN * 96) + 8 * (lane % 12);
    if (isbf) {
      const unsigned short* xb = (const unsigned short*)x;
      int j = 0;
      for (; j + 1 < m1; j += 2) {
        int2 e0 = svw[j], e1 = svw[j + 1];
        uint4 u0 = *(const uint4*)(xb + xbase + e0.x);
        uint4 u1 = *(const uint4*)(xb + xbase + e1.x);
        float v0 = __int_as_float(e0.y), v1 = __int_as_float(e1.y);
        ACC8(u0, v0); ACC8(u1, v1);
      }
      if (j < m1) {
        int2 e0 = svw[j];
        uint4 u0 = *(const uint4*)(xb + xbase + e0.x);
        float v0 = __int_as_float(e0.y);
        ACC8(u0, v0);
      }
    } else {
      const float* xf = (const float*)x;
      int j = 0;
      for (; j + 1 < m1; j += 2) {
        int2 e0 = svw[j], e1 = svw[j + 1];
        const float4* p0 = (const float4*)(xf + xbase + e0.x);
        const float4* p1 = (const float4*)(xf + xbase + e1.x);
        float4 u00 = p0[0], u01 = p0[1], u10 = p1[0], u11 = p1[1];
        float v0 = __int_as_float(e0.y), v1 = __int_as_float(e1.y);
        ACCF8(u00, u01, v0); ACCF8(u10, u11, v1);
      }
      if (j < m1) {
        int2 e0 = svw[j];
        const float4* p0 = (const float4*)(xf + xbase + e0.x);
        float4 u00 = p0[0], u01 = p0[1];
        float v0 = __int_as_float(e0.y);
        ACCF8(u00, u01, v0);
      }
    }
    // scatter-transpose into accT[b][p][f], scaled by dn
    float* accTw = &accT[w * 384];
    const int bq = (lane / 12) * 96, oc = 8 * (lane % 12);
#pragma unroll
    for (int t = 0; t < 8; ++t) {
      int eib = oc + t;
      int f = eib / 12, p = eib % 12;
      accTw[bq + p * 8 + f] = dn * a[t];
    }
  }
  __builtin_amdgcn_wave_barrier();

  // --- gates: lane = hidden index k; all 48 (b,p) pairs; h accumulated per b ---
  {
    const float* accTw = &accT[w * 384];
    float* hww = &hw[w * 272];
#pragma unroll
    for (int b = 0; b < 4; ++b) {
      float hbl = 0.f;
#pragma unroll
      for (int p = 0; p < 12; ++p) {
        const float4* A = (const float4*)&accTw[b * 96 + p * 8];
        float4 A0 = A[0], A1 = A[1];
        float za = bz + A0.x * wz[0] + A0.y * wz[1] + A0.z * wz[2] + A0.w * wz[3]
                      + A1.x * wz[4] + A1.y * wz[5] + A1.z * wz[6] + A1.w * wz[7];
        float ta = bh + A0.x * wh[0] + A0.y * wh[1] + A0.z * wh[2] + A0.w * wh[3]
                      + A1.x * wh[4] + A1.y * wh[5] + A1.z * wh[6] + A1.w * wh[7];
        // (1 - sigmoid(za)) * tanh(ta) = (eh-1) / ((1+ea)(1+eh)), ea=e^za, eh=e^{2ta}
        float ea = __expf(za);
        float eh = __expf(2.0f * fminf(ta, 40.0f));
        hbl += sow[828 + p] * (eh - 1.0f) *
               __builtin_amdgcn_rcpf((1.0f + ea) * (1.0f + eh));
      }
      hww[b * 68 + lane] = fmaxf(hbl, 0.f);   // relu
    }
  }
  __builtin_amdgcn_wave_barrier();

  // --- out projection: lane t<48 -> (b,p); vectorized b128 reads ---
  if (lane < 48) {
    const float* hww = &hw[w * 272];
    int b = lane / 12, p = lane % 12;
    float o = sow[816 + p];
#pragma unroll
    for (int kq = 0; kq < 16; ++kq) {
      float4 hv = *(const float4*)&hww[b * 68 + 4 * kq];
      float4 wv = *(const float4*)&sow[p * 68 + 4 * kq];
      o += hv.x * wv.x + hv.y * wv.y + hv.z * wv.z + hv.w * wv.w;
    }
    int oi = (b * NN + n) * 12 + p;
    if (isbf) ((unsigned short*)out)[oi] = f2b(o);
    else      ((float*)out)[oi] = o;
  }
}

extern "C" void kernel_launch(void* const* d_in, const int* in_sizes, int n_in,
                              void* d_out, int out_size, void* d_ws, size_t ws_size,
                              hipStream_t stream) {
  const void* x   = d_in[0];
  const void* ei  = d_in[1];
  const void* ea  = d_in[2];
  const void* czw = d_in[3];
  const void* czb = d_in[4];
  // d_in[5], d_in[6]: conv_r_* — dead (H0 = 0)
  const void* chw = d_in[7];
  const void* chb = d_in[8];
  const void* lzw = d_in[9];
  const void* lzb = d_in[10];
  // d_in[11], d_in[12]: lin_r_* — dead
  const void* lhw = d_in[13];
  const void* lhb = d_in[14];
  const void* att = d_in[15];
  const void* ow  = d_in[16];
  const void* ob  = d_in[17];

  // workspace ~6.5 MB
  char* ws = (char*)d_ws;
  int*   flags   = (int*)  (ws + 0);
  float* consts  = (float*)(ws + 256);              // 1992 f32 -> ends 8224
  unsigned long long* degcnt = (unsigned long long*)(ws + 8704);  // 1,280,000 B padded
  int*   ovf_cnt = (int*)  (ws + 1288704);          // contiguous with degcnt for memset
  int*   ovf_dst = (int*)  (ws + 1288768);          // 32768 -> 1,321,536
  unsigned int* ovf_pack = (unsigned int*)(ws + 1321536);  // 32768 -> 1,354,304
  unsigned int* slab     = (unsigned int*)(ws + 1354304);  // 5,120,000 -> 6,474,304

  // zero degcnt + ovf_cnt in one DMA fill (replaces k_init's zero pass)
  hipMemsetAsync(ws + 8704, 0, 1280064, stream);
  k_append<<<dim3(EBLK + 1), dim3(256), 0, stream>>>(ei, ea, degcnt, slab,
                                                     ovf_cnt, ovf_dst, ovf_pack,
                                                     flags, consts,
                                                     czw, czb, chw, chb,
                                                     lzw, lzb, lhw, lhb,
                                                     att, ow, ob);
  k_node<<<dim3(NN / 4), dim3(256), 0, stream>>>(x, degcnt, slab, ovf_cnt, ovf_dst,
                                                 ovf_pack, consts, flags, d_out);
}